// Round 1
// baseline (203.649 us; speedup 1.0000x reference)
//
#include <hip/hip_runtime.h>
#include <math.h>

// QLSTM on MI355X.
// Structure: (1) xw precompute kernel (parallel, coalesced) into d_ws,
//            (2) recurrent kernel, 4 lanes/element (one per gate f,i,u,o),
//                16-complex-amp statevector fully in registers, unrolled.
// Serial T=64 loop; parallelism limited to B=1024 elements * 4 gates.

#define NQ 4
#define NL 2
#define BB 1024
#define TT 64
#define FF 32
#define HH 8

// ---------------- kernel 1: xw[t][b][g] = b_in[g] + x[b,t,:] . w_in[g, 8:40]
__global__ __launch_bounds__(256)
void xw_kernel(const float* __restrict__ x,
               const float* __restrict__ w_in,
               const float* __restrict__ b_in,
               float* __restrict__ xw) {
    int tid = blockIdx.x * blockDim.x + threadIdx.x;   // 0 .. 262143
    int g  = tid & 3;
    int bt = tid >> 2;            // t*1024 + b
    int t  = bt >> 10;
    int b  = bt & 1023;
    const float* xr = x + (b * TT + t) * FF;
    float acc = b_in[g];
    #pragma unroll
    for (int k = 0; k < FF; k += 4) {
        float4 xv = *reinterpret_cast<const float4*>(xr + k);
        acc = fmaf(xv.x, w_in[g*40 + 8  + k], acc);
        acc = fmaf(xv.y, w_in[g*40 + 9  + k], acc);
        acc = fmaf(xv.z, w_in[g*40 + 10 + k], acc);
        acc = fmaf(xv.w, w_in[g*40 + 11 + k], acc);
    }
    xw[tid] = acc;
}

// ---------------- RX / CNOT on register statevector ------------------------
// amp index b = wire0<<3 | wire1<<2 | wire2<<1 | wire3  (wire w <-> bit 3-w)
#define RX_W(wv, cc, ss) do {                                   \
    const int str_ = 8 >> (wv);                                 \
    _Pragma("unroll")                                           \
    for (int lo_ = 0; lo_ < 16; ++lo_) {                        \
      if ((lo_ & str_) == 0) {                                  \
        const int hi_ = lo_ | str_;                             \
        float a0r = ar[lo_], a0i = ai[lo_];                     \
        float a1r = ar[hi_], a1i = ai[hi_];                     \
        ar[lo_] = fmaf((cc), a0r,  (ss)*a1i);                   \
        ai[lo_] = fmaf((cc), a0i, -(ss)*a1r);                   \
        ar[hi_] = fmaf((cc), a1r,  (ss)*a0i);                   \
        ai[hi_] = fmaf((cc), a1i, -(ss)*a0r);                   \
      }                                                         \
    }                                                           \
} while (0)

#define CNOT_W(cw, tw) do {                                     \
    const int cb_ = 1 << (3-(cw));                              \
    const int tb_ = 1 << (3-(tw));                              \
    _Pragma("unroll")                                           \
    for (int ix_ = 0; ix_ < 16; ++ix_) {                        \
      if ((ix_ & cb_) && !(ix_ & tb_)) {                        \
        const int jx_ = ix_ | tb_;                              \
        float tr_ = ar[ix_]; ar[ix_] = ar[jx_]; ar[jx_] = tr_;  \
        float ti_ = ai[ix_]; ai[ix_] = ai[jx_]; ai[jx_] = ti_;  \
      }                                                         \
    }                                                           \
} while (0)

// ---------------- kernel 2: recurrence, 4 lanes per batch element ----------
template <bool USE_XW>
__global__ __launch_bounds__(64)
void qlstm_kernel(const float* __restrict__ xw,      // [T][B][4] or null
                  const float* __restrict__ x,       // fallback path
                  const float* __restrict__ w_in,
                  const float* __restrict__ b_in,
                  const float* __restrict__ w_out,
                  const float* __restrict__ b_out,
                  const float* __restrict__ wq_f,
                  const float* __restrict__ wq_i,
                  const float* __restrict__ wq_u,
                  const float* __restrict__ wq_o,
                  const float* __restrict__ w_fc,
                  const float* __restrict__ b_fc,
                  float* __restrict__ out) {
    const int tid  = blockIdx.x * 64 + threadIdx.x;  // 0..4095
    const int g    = tid & 3;                        // gate: 0=f 1=i 2=u 3=o
    const int elem = tid >> 2;                       // batch element

    // per-lane h-part weights of w_in row g
    float wh[HH];
    #pragma unroll
    for (int j = 0; j < HH; ++j) wh[j] = w_in[g*40 + j];

    // fixed circuit angles for this lane's gate -> cos/sin once
    const float* wq = (g == 0) ? wq_f : (g == 1) ? wq_i : (g == 2) ? wq_u : wq_o;
    float lc[NL*NQ], ls[NL*NQ];
    #pragma unroll
    for (int a = 0; a < NL*NQ; ++a) {
        float ang = wq[a] * 0.5f;
        lc[a] = __cosf(ang);
        ls[a] = __sinf(ang);
    }

    float wo[HH*NQ];
    #pragma unroll
    for (int a = 0; a < HH*NQ; ++a) wo[a] = w_out[a];
    float bo[HH];
    #pragma unroll
    for (int j = 0; j < HH; ++j) bo[j] = b_out[j];

    // unified activation: sigmoid for f,i,o ; tanh = 2*sigmoid(2x)-1 for u
    const bool  isG  = (g == 2);
    const float inS  = isG ? 2.0f : 1.0f;
    const float outS = isG ? 2.0f : 1.0f;
    const float outB = isG ? -1.0f : 0.0f;

    float bin_g = b_in[g];

    float h[HH], c[HH];
    #pragma unroll
    for (int j = 0; j < HH; ++j) { h[j] = 0.0f; c[j] = 0.0f; }

    for (int t = 0; t < TT; ++t) {
        // ---- y_g = xw + h . wh
        float y;
        if (USE_XW) {
            y = xw[t*(BB*4) + tid];                  // fully coalesced
        } else {
            y = bin_g;
            const float* xr = x + (elem * TT + t) * FF;
            #pragma unroll
            for (int k = 0; k < FF; k += 4) {
                float4 xv = *reinterpret_cast<const float4*>(xr + k);
                y = fmaf(xv.x, w_in[g*40 + 8  + k], y);
                y = fmaf(xv.y, w_in[g*40 + 9  + k], y);
                y = fmaf(xv.z, w_in[g*40 + 10 + k], y);
                y = fmaf(xv.w, w_in[g*40 + 11 + k], y);
            }
        }
        #pragma unroll
        for (int j = 0; j < HH; ++j) y = fmaf(h[j], wh[j], y);

        // ---- share cos/sin of all 4 y-angles within the 4-lane group
        float cs = __cosf(0.5f * y);
        float sn = __sinf(0.5f * y);
        float c0 = __shfl(cs, 0, 4), c1 = __shfl(cs, 1, 4);
        float c2 = __shfl(cs, 2, 4), c3 = __shfl(cs, 3, 4);
        float s0 = __shfl(sn, 0, 4), s1 = __shfl(sn, 1, 4);
        float s2 = __shfl(sn, 2, 4), s3 = __shfl(sn, 3, 4);

        // ---- initial product state: amp[b] = (-i)^popcount(b) * prod(mags)
        float m01[4], m23[4];
        m01[0] = c0*c1; m01[1] = c0*s1; m01[2] = s0*c1; m01[3] = s0*s1;
        m23[0] = c2*c3; m23[1] = c2*s3; m23[2] = s2*c3; m23[3] = s2*s3;

        float ar[16], ai[16];
        #pragma unroll
        for (int b0 = 0; b0 < 2; ++b0)
        #pragma unroll
        for (int b1 = 0; b1 < 2; ++b1)
        #pragma unroll
        for (int b2 = 0; b2 < 2; ++b2)
        #pragma unroll
        for (int b3 = 0; b3 < 2; ++b3) {
            const int idx = (b0<<3) | (b1<<2) | (b2<<1) | b3;
            const int pc  = (b0+b1+b2+b3) & 3;
            float m = m01[(b0<<1)|b1] * m23[(b2<<1)|b3];
            float re, im;
            if (pc == 0)      { re =  m;    im = 0.0f; }
            else if (pc == 1) { re = 0.0f;  im = -m;   }
            else if (pc == 2) { re = -m;    im = 0.0f; }
            else              { re = 0.0f;  im =  m;   }
            ar[idx] = re; ai[idx] = im;
        }

        // ---- this lane's gate circuit: NL x (RX on all wires, CNOT ring)
        #pragma unroll
        for (int l = 0; l < NL; ++l) {
            RX_W(0, lc[l*4+0], ls[l*4+0]);
            RX_W(1, lc[l*4+1], ls[l*4+1]);
            RX_W(2, lc[l*4+2], ls[l*4+2]);
            RX_W(3, lc[l*4+3], ls[l*4+3]);
            CNOT_W(0, 1);
            CNOT_W(1, 2);
            CNOT_W(2, 3);
            CNOT_W(3, 0);
        }

        // ---- Z expectations
        float e0 = 0.f, e1 = 0.f, e2 = 0.f, e3 = 0.f;
        #pragma unroll
        for (int idx = 0; idx < 16; ++idx) {
            float p = fmaf(ar[idx], ar[idx], ai[idx]*ai[idx]);
            e0 += (idx & 8) ? -p : p;
            e1 += (idx & 4) ? -p : p;
            e2 += (idx & 2) ? -p : p;
            e3 += (idx & 1) ? -p : p;
        }

        // ---- gate vector: (e @ w_out.T + b_out) -> activation
        float act[HH];
        #pragma unroll
        for (int j = 0; j < HH; ++j) {
            float a = bo[j];
            a = fmaf(e0, wo[j*4+0], a);
            a = fmaf(e1, wo[j*4+1], a);
            a = fmaf(e2, wo[j*4+2], a);
            a = fmaf(e3, wo[j*4+3], a);
            float sg = 1.0f / (1.0f + __expf(-inS * a));
            act[j] = fmaf(sg, outS, outB);
        }

        // ---- exchange gates within the 4-lane group, cell update (replicated)
        #pragma unroll
        for (int j = 0; j < HH; ++j) {
            float fv = __shfl(act[j], 0, 4);
            float iv = __shfl(act[j], 1, 4);
            float gv = __shfl(act[j], 2, 4);
            float ov = __shfl(act[j], 3, 4);
            float cn = fmaf(fv, c[j], iv * gv);
            c[j] = cn;
            float th = 2.0f / (1.0f + __expf(-2.0f * cn)) - 1.0f;  // tanh
            h[j] = ov * th;
        }
    }

    if (g == 0) {
        float r = b_fc[0];
        #pragma unroll
        for (int j = 0; j < HH; ++j) r = fmaf(h[j], w_fc[j], r);
        out[elem] = r;
    }
}

extern "C" void kernel_launch(void* const* d_in, const int* in_sizes, int n_in,
                              void* d_out, int out_size, void* d_ws, size_t ws_size,
                              hipStream_t stream) {
    const float* x     = (const float*)d_in[0];
    const float* w_in  = (const float*)d_in[1];
    const float* b_in  = (const float*)d_in[2];
    const float* w_out = (const float*)d_in[3];
    const float* b_out = (const float*)d_in[4];
    const float* wq_f  = (const float*)d_in[5];
    const float* wq_i  = (const float*)d_in[6];
    const float* wq_u  = (const float*)d_in[7];
    const float* wq_o  = (const float*)d_in[8];
    const float* w_fc  = (const float*)d_in[9];
    const float* b_fc  = (const float*)d_in[10];
    float* out = (float*)d_out;

    const size_t xw_bytes = (size_t)TT * BB * 4 * sizeof(float);  // 1 MiB
    if (ws_size >= xw_bytes) {
        float* xw = (float*)d_ws;
        xw_kernel<<<(TT*BB*4)/256, 256, 0, stream>>>(x, w_in, b_in, xw);
        qlstm_kernel<true><<<64, 64, 0, stream>>>(xw, x, w_in, b_in, w_out, b_out,
                                                  wq_f, wq_i, wq_u, wq_o,
                                                  w_fc, b_fc, out);
    } else {
        qlstm_kernel<false><<<64, 64, 0, stream>>>(nullptr, x, w_in, b_in, w_out, b_out,
                                                   wq_f, wq_i, wq_u, wq_o,
                                                   w_fc, b_fc, out);
    }
}

// Round 2
// 130.477 us; speedup vs baseline: 1.5608x; 1.5608x over previous
//
#include <hip/hip_runtime.h>
#include <math.h>

// QLSTM via exact Heisenberg/polynomial reformulation.
// e_w = <s0| U^dag Z_w U |s0> with s0 = prod RX(y_q)|0>.  Since
// <RX(y)0|P|RX(y)0> = {I:1, X:0, Y:-sin y, Z:cos y}, each gate pre-activation
// is an exact multilinear polynomial in (1, u_q=cos y_q, v_q=sin y_q):
//   a_j^g = sum_t D[g][j][t] * prod_q basis(t_q),  t in {0,1,2}^4  (81 coeffs)
// D is computed at launch (K1: build U_g; K2: fold into D), then the
// recurrence (K3) evaluates the polynomial: 80 FMA per (gate,unit) lane.

#define NQ 4
#define NL 2
#define BB 1024
#define TT 64
#define FF 32
#define HH 8

// ws layout (floats): Ure[4*16*16] @0, Uim @1024, D[4*8*84] @2048
#define WS_URE 0
#define WS_UIM 1024
#define WS_D   2048

// ---- register statevector circuit macros (verified in round 1) -----------
// amp index b = wire0<<3 | wire1<<2 | wire2<<1 | wire3
#define RX_W(wv, cc, ss) do {                                   \
    const int str_ = 8 >> (wv);                                 \
    _Pragma("unroll")                                           \
    for (int lo_ = 0; lo_ < 16; ++lo_) {                        \
      if ((lo_ & str_) == 0) {                                  \
        const int hi_ = lo_ | str_;                             \
        float a0r = ar[lo_], a0i = ai[lo_];                     \
        float a1r = ar[hi_], a1i = ai[hi_];                     \
        ar[lo_] = fmaf((cc), a0r,  (ss)*a1i);                   \
        ai[lo_] = fmaf((cc), a0i, -(ss)*a1r);                   \
        ar[hi_] = fmaf((cc), a1r,  (ss)*a0i);                   \
        ai[hi_] = fmaf((cc), a1i, -(ss)*a0r);                   \
      }                                                         \
    }                                                           \
} while (0)

#define CNOT_W(cw, tw) do {                                     \
    const int cb_ = 1 << (3-(cw));                              \
    const int tb_ = 1 << (3-(tw));                              \
    _Pragma("unroll")                                           \
    for (int ix_ = 0; ix_ < 16; ++ix_) {                        \
      if ((ix_ & cb_) && !(ix_ & tb_)) {                        \
        const int jx_ = ix_ | tb_;                              \
        float tr_ = ar[ix_]; ar[ix_] = ar[jx_]; ar[jx_] = tr_;  \
        float ti_ = ai[ix_]; ai[ix_] = ai[jx_]; ai[jx_] = ti_;  \
      }                                                         \
    }                                                           \
} while (0)

// ---------------- K1: build the 4 fixed 16x16 unitaries --------------------
// lane = (g<<4)|col : column col of U_g.  U[g][m][col] stored to ws.
__global__ __launch_bounds__(64)
void build_u_kernel(const float* __restrict__ wq_f,
                    const float* __restrict__ wq_i,
                    const float* __restrict__ wq_u,
                    const float* __restrict__ wq_o,
                    float* __restrict__ ws) {
    const int lane = threadIdx.x;
    const int g   = lane >> 4;
    const int col = lane & 15;
    const float* wq = (g == 0) ? wq_f : (g == 1) ? wq_i : (g == 2) ? wq_u : wq_o;
    float lc[NL*NQ], ls[NL*NQ];
    #pragma unroll
    for (int a = 0; a < NL*NQ; ++a) {
        float ang = wq[a] * 0.5f;
        lc[a] = __cosf(ang);
        ls[a] = __sinf(ang);
    }
    float ar[16], ai[16];
    #pragma unroll
    for (int m = 0; m < 16; ++m) { ar[m] = (m == col) ? 1.0f : 0.0f; ai[m] = 0.0f; }
    #pragma unroll
    for (int l = 0; l < NL; ++l) {
        RX_W(0, lc[l*4+0], ls[l*4+0]);
        RX_W(1, lc[l*4+1], ls[l*4+1]);
        RX_W(2, lc[l*4+2], ls[l*4+2]);
        RX_W(3, lc[l*4+3], ls[l*4+3]);
        CNOT_W(0, 1); CNOT_W(1, 2); CNOT_W(2, 3); CNOT_W(3, 0);
    }
    float* Ure = ws + WS_URE;
    float* Uim = ws + WS_UIM;
    #pragma unroll
    for (int m = 0; m < 16; ++m) {
        Ure[g*256 + m*16 + col] = ar[m];
        Uim[g*256 + m*16 + col] = ai[m];
    }
}

// ---------------- K2: fold U into coefficient tensor D ---------------------
// block = (g<<3)|ju. Phase 1: Bmat[a][b] = sum_m A[m] conj(U[m,a]) U[m,b]
// with A[m] = sum_w w_out[ju,w]*z_w(m).  Phase 2 (81 threads): per t,
// D[g][ju][t] = sum_{s in {0,1}^4} Re( W(s,t) * Bmat[j(s,t)][k(s,t)] )
//               (+ b_out[ju] at t==0)
__global__ __launch_bounds__(128)
void build_d_kernel(const float* __restrict__ w_out,
                    const float* __restrict__ b_out,
                    float* __restrict__ ws) {
    __shared__ float sBre[256], sBim[256];
    const int g  = blockIdx.x >> 3;
    const int ju = blockIdx.x & 7;
    const int tid = threadIdx.x;

    const float* Ure = ws + WS_URE + g*256;
    const float* Uim = ws + WS_UIM + g*256;

    float A[16];
    #pragma unroll
    for (int m = 0; m < 16; ++m) {
        float a = 0.0f;
        #pragma unroll
        for (int w = 0; w < 4; ++w) {
            float sgn = ((m >> (3-w)) & 1) ? -1.0f : 1.0f;
            a = fmaf(w_out[ju*4 + w], sgn, a);
        }
        A[m] = a;
    }
    // phase 1: 2 entries per thread
    #pragma unroll
    for (int r = 0; r < 2; ++r) {
        int e = tid + r*128;
        int ja = e >> 4, kb = e & 15;
        float br = 0.0f, bi = 0.0f;
        #pragma unroll
        for (int m = 0; m < 16; ++m) {
            float ujr = Ure[m*16 + ja], uji = Uim[m*16 + ja];
            float ukr = Ure[m*16 + kb], uki = Uim[m*16 + kb];
            float pr = ujr*ukr + uji*uki;        // conj(Uj)*Uk
            float pi = ujr*uki - uji*ukr;
            br = fmaf(A[m], pr, br);
            bi = fmaf(A[m], pi, bi);
        }
        sBre[e] = br; sBim[e] = bi;
    }
    __syncthreads();

    if (tid < 81) {
        const int t = tid;
        int tq[4];
        tq[0] = t / 27; tq[1] = (t / 9) % 3; tq[2] = (t / 3) % 3; tq[3] = t % 3;
        float acc = 0.0f;
        for (int s = 0; s < 16; ++s) {
            int jj = 0, kk = 0;
            float Wre = 1.0f, Wim = 0.0f;
            #pragma unroll
            for (int q = 0; q < 4; ++q) {
                int sq = (s >> q) & 1;
                int bit = 1 << (3-q);
                if (tq[q] == 2) {
                    // j_q = s, k_q = 1-s ; weight = (s? +i/2 : -i/2)
                    if (sq) jj |= bit; else kk |= bit;
                    float cm = sq ? 0.5f : -0.5f;
                    float nr = -Wim * cm;
                    float ni =  Wre * cm;
                    Wre = nr; Wim = ni;
                } else {
                    if (sq) { jj |= bit; kk |= bit; }
                    float cm = (tq[q] == 1 && sq) ? -0.5f : 0.5f;
                    Wre *= cm; Wim *= cm;
                }
            }
            float br = sBre[jj*16 + kk], bi = sBim[jj*16 + kk];
            acc += Wre*br - Wim*bi;
        }
        if (t == 0) acc += b_out[ju];
        ws[WS_D + (g*8 + ju)*84 + t] = acc;
    }
}

// ---------------- K3: recurrence, 32 lanes per element ---------------------
// lane = w + 4*j + 32*half.  w doubles as wire id (for y) and gate id
// (for the polynomial / activation).  2 elements per 64-thread block.
__global__ __launch_bounds__(64, 1)
void qlstm_poly_kernel(const float* __restrict__ x,
                       const float* __restrict__ w_in,
                       const float* __restrict__ b_in,
                       const float* __restrict__ w_fc,
                       const float* __restrict__ b_fc,
                       const float* __restrict__ ws,
                       float* __restrict__ out) {
    const int lane = threadIdx.x;
    const int w    = lane & 3;
    const int j    = (lane >> 2) & 7;
    const int half = lane >> 5;
    const int elem = blockIdx.x * 2 + half;
    const int base_q = lane & 32;    // lane holding qubit q's (u,v): base_q|q
    const int base_g = lane & ~3;    // lane holding gate m's act : base_g|m

    // load this lane's 81 polynomial coefficients
    const float* Dp = ws + WS_D + (w*8 + j)*84;
    float D[81];
    #pragma unroll
    for (int i = 0; i < 20; ++i) {
        float4 tv = *reinterpret_cast<const float4*>(Dp + 4*i);
        D[4*i+0] = tv.x; D[4*i+1] = tv.y; D[4*i+2] = tv.z; D[4*i+3] = tv.w;
    }
    D[80] = Dp[80];

    const float wh  = w_in[w*40 + j];
    const float4 wx = *reinterpret_cast<const float4*>(w_in + w*40 + 8 + 4*j);
    const float bin = b_in[w];
    const float wfc = w_fc[j];

    const bool  isG  = (w == 2);
    const float inS  = isG ? 2.0f : 1.0f;
    const float outS = isG ? 2.0f : 1.0f;
    const float outB = isG ? -1.0f : 0.0f;

    const float* xrow = x + elem * (TT*FF);
    float4 xv = *reinterpret_cast<const float4*>(xrow + 4*j);   // t=0

    float cc = 0.0f, hh = 0.0f;   // this lane's c[j], h[j]

    for (int t = 0; t < TT; ++t) {
        // prefetch next timestep's x fragment (independent of recurrence)
        const int tn = (t + 1) & 63;
        float4 xn = *reinterpret_cast<const float4*>(xrow + tn*FF + 4*j);

        // ---- y_w = b_in[w] + x.w_in[w,8:] + h.w_in[w,:8]  (j-distributed)
        float p = fmaf(xv.x, wx.x, fmaf(xv.y, wx.y, fmaf(xv.z, wx.z, xv.w*wx.w)));
        p = fmaf(hh, wh, p);
        p += __shfl_xor(p, 4);
        p += __shfl_xor(p, 8);
        p += __shfl_xor(p, 16);
        const float y = p + bin;

        // ---- per-wire basis, broadcast to all lanes in qubit order
        const float u = __cosf(y);
        const float v = __sinf(y);
        const float u0 = __shfl(u, base_q | 0), v0 = __shfl(v, base_q | 0);
        const float u1 = __shfl(u, base_q | 1), v1 = __shfl(v, base_q | 1);
        const float u2 = __shfl(u, base_q | 2), v2 = __shfl(v, base_q | 2);
        const float u3 = __shfl(u, base_q | 3), v3 = __shfl(v, base_q | 3);

        // ---- factored 81-term contraction (80 FMA)
        float c3[27];
        #pragma unroll
        for (int i = 0; i < 27; ++i)
            c3[i] = fmaf(u3, D[3*i+1], fmaf(v3, D[3*i+2], D[3*i]));
        float c2[9];
        #pragma unroll
        for (int i = 0; i < 9; ++i)
            c2[i] = fmaf(u2, c3[3*i+1], fmaf(v2, c3[3*i+2], c3[3*i]));
        float c1[3];
        #pragma unroll
        for (int i = 0; i < 3; ++i)
            c1[i] = fmaf(u1, c2[3*i+1], fmaf(v1, c2[3*i+2], c2[3*i]));
        const float a = fmaf(u0, c1[1], fmaf(v0, c1[2], c1[0]));

        // ---- activation (sigmoid; tanh = 2*sigmoid(2a)-1 for gate u)
        const float sg  = 1.0f / (1.0f + __expf(-inS * a));
        const float act = fmaf(sg, outS, outB);

        // ---- gather the 4 gate values for this hidden unit
        const float fv = __shfl(act, base_g | 0);
        const float iv = __shfl(act, base_g | 1);
        const float gv = __shfl(act, base_g | 2);
        const float ov = __shfl(act, base_g | 3);

        // ---- cell update
        cc = fmaf(fv, cc, iv * gv);
        const float th = 2.0f / (1.0f + __expf(-2.0f * cc)) - 1.0f;
        hh = ov * th;

        xv = xn;
    }

    // ---- out[b] = h . w_fc + b_fc  (reduce over j)
    float pr = hh * wfc;
    pr += __shfl_xor(pr, 4);
    pr += __shfl_xor(pr, 8);
    pr += __shfl_xor(pr, 16);
    if ((lane & 31) == 0) out[elem] = pr + b_fc[0];
}

extern "C" void kernel_launch(void* const* d_in, const int* in_sizes, int n_in,
                              void* d_out, int out_size, void* d_ws, size_t ws_size,
                              hipStream_t stream) {
    const float* x     = (const float*)d_in[0];
    const float* w_in  = (const float*)d_in[1];
    const float* b_in  = (const float*)d_in[2];
    const float* w_out = (const float*)d_in[3];
    const float* b_out = (const float*)d_in[4];
    const float* wq_f  = (const float*)d_in[5];
    const float* wq_i  = (const float*)d_in[6];
    const float* wq_u  = (const float*)d_in[7];
    const float* wq_o  = (const float*)d_in[8];
    const float* w_fc  = (const float*)d_in[9];
    const float* b_fc  = (const float*)d_in[10];
    float* out = (float*)d_out;
    float* ws  = (float*)d_ws;
    (void)in_sizes; (void)n_in; (void)out_size; (void)ws_size;

    build_u_kernel<<<1, 64, 0, stream>>>(wq_f, wq_i, wq_u, wq_o, ws);
    build_d_kernel<<<32, 128, 0, stream>>>(w_out, b_out, ws);
    qlstm_poly_kernel<<<BB/2, 64, 0, stream>>>(x, w_in, b_in, w_fc, b_fc, ws, out);
}

// Round 3
// 114.287 us; speedup vs baseline: 1.7819x; 1.1417x over previous
//
#include <hip/hip_runtime.h>
#include <math.h>

// QLSTM, single-kernel exact-polynomial formulation.
// Gate pre-activation a^g_j(y) is exactly multilinear in per-wire basis
// (1, cos y_q, sin y_q) -> 81 coeffs per (gate, unit).  Each block:
//  P1: stage xw = b_in + x.w_in into LDS (removes global loads from loop)
//  P2: evaluate e_w for each gate at the 81 grid points y_q in {0, ±2pi/3}
//      (constant init states; circuit simulated in registers)
//  P3: per-axis 3-point inverse transform in LDS -> coefficient tensors C
//  P4: each lane folds C with w_out/b_out -> its private D[81]
//  Main loop: 1 DS level per step (8 parallel ds_bpermute to collect h);
//  act-gather and u/v-broadcast via DPP quad_perm (VALU, not DS).

#define NQ 4
#define NL 2
#define BB 1024
#define TT 64
#define FF 32
#define HH 8

// ---- register statevector circuit macros (verified rounds 1-2) -----------
// amp index b = wire0<<3 | wire1<<2 | wire2<<1 | wire3
#define RX_W(wv, cc, ss) do {                                   \
    const int str_ = 8 >> (wv);                                 \
    _Pragma("unroll")                                           \
    for (int lo_ = 0; lo_ < 16; ++lo_) {                        \
      if ((lo_ & str_) == 0) {                                  \
        const int hi_ = lo_ | str_;                             \
        float a0r = ar[lo_], a0i = ai[lo_];                     \
        float a1r = ar[hi_], a1i = ai[hi_];                     \
        ar[lo_] = fmaf((cc), a0r,  (ss)*a1i);                   \
        ai[lo_] = fmaf((cc), a0i, -(ss)*a1r);                   \
        ar[hi_] = fmaf((cc), a1r,  (ss)*a0i);                   \
        ai[hi_] = fmaf((cc), a1i, -(ss)*a0r);                   \
      }                                                         \
    }                                                           \
} while (0)

#define CNOT_W(cw, tw) do {                                     \
    const int cb_ = 1 << (3-(cw));                              \
    const int tb_ = 1 << (3-(tw));                              \
    _Pragma("unroll")                                           \
    for (int ix_ = 0; ix_ < 16; ++ix_) {                        \
      if ((ix_ & cb_) && !(ix_ & tb_)) {                        \
        const int jx_ = ix_ | tb_;                              \
        float tr_ = ar[ix_]; ar[ix_] = ar[jx_]; ar[jx_] = tr_;  \
        float ti_ = ai[ix_]; ai[ix_] = ai[jx_]; ai[jx_] = ti_;  \
      }                                                         \
    }                                                           \
} while (0)

// DPP quad_perm broadcast of quad position K (VALU-latency cross-lane)
#define QUAD_BCAST(x, CTRL) \
    __int_as_float(__builtin_amdgcn_mov_dpp(__float_as_int(x), (CTRL), 0xf, 0xf, true))

// in-place 3-point inverse transform along one axis (stride ST) of sC rows
#define TPASS(ST) do {                                                       \
    for (int i_ = threadIdx.x; i_ < 432; i_ += 64) {                         \
      int gw_ = i_ / 27; int r_ = i_ - gw_*27;                               \
      int hi_ = r_ / (ST); int lo_ = r_ - hi_*(ST);                          \
      float* row_ = sC + gw_*84; int p0_ = hi_*3*(ST) + lo_;                 \
      float f0_ = row_[p0_], f1_ = row_[p0_+(ST)], f2_ = row_[p0_+2*(ST)];   \
      row_[p0_]          = (f0_ + f1_ + f2_) * 0.3333333333333333f;          \
      row_[p0_+(ST)]     = (2.0f*f0_ - f1_ - f2_) * 0.3333333333333333f;     \
      row_[p0_+2*(ST)]   = (f1_ - f2_) * 0.5773502691896258f;                \
    }                                                                        \
    __syncthreads();                                                         \
} while (0)

__global__ __launch_bounds__(64, 1)
void qlstm_fused_kernel(const float* __restrict__ x,
                        const float* __restrict__ w_in,
                        const float* __restrict__ b_in,
                        const float* __restrict__ w_out,
                        const float* __restrict__ b_out,
                        const float* __restrict__ wq_f,
                        const float* __restrict__ wq_i,
                        const float* __restrict__ wq_u,
                        const float* __restrict__ wq_o,
                        const float* __restrict__ w_fc,
                        const float* __restrict__ b_fc,
                        float* __restrict__ out) {
    __shared__ float sC[16 * 84];      // [g*4+w][coeff 0..80]
    __shared__ float sXW[2 * 65 * 4];  // [half][t][w], padded

    const int lane = threadIdx.x;
    const int w    = lane & 3;         // wire id AND gate id for this lane
    const int j    = (lane >> 2) & 7;  // hidden unit
    const int half = lane >> 5;
    const int elem = blockIdx.x * 2 + half;

    // ---------------- P1: stage xw[half][t][w] = b_in[w] + x[elem,t,:].w_in[w,8:]
    {
        const int idx = lane & 31;
        const float* xrow = x + (size_t)elem * (TT * FF);
        #pragma unroll
        for (int r = 0; r < 8; ++r) {
            int slot = idx + 32 * r;       // 0..255
            int tt = slot >> 2;
            int ww = slot & 3;
            float acc = b_in[ww];
            const float* wrow = w_in + ww * 40 + 8;
            #pragma unroll
            for (int k = 0; k < FF; k += 4) {
                float4 xv = *reinterpret_cast<const float4*>(xrow + tt * FF + k);
                acc = fmaf(xv.x, wrow[k],     acc);
                acc = fmaf(xv.y, wrow[k + 1], acc);
                acc = fmaf(xv.z, wrow[k + 2], acc);
                acc = fmaf(xv.w, wrow[k + 3], acc);
            }
            sXW[(half * 65 + tt) * 4 + ww] = acc;
        }
    }

    // ---------------- P2: simulate circuit at 81 constant grid points ----------
    // grid y in {0, 2pi/3, -2pi/3}; half-angle cos in {1, 1/2, 1/2},
    // sin in {0, +s3h, -s3h}
    for (int sidx = lane; sidx < 324; sidx += 64) {
        int g = sidx / 81;
        int p = sidx - g * 81;
        int t0 = p / 27; int rem = p - t0 * 27;
        int t1 = rem / 9; rem -= t1 * 9;
        int t2 = rem / 3; int t3 = rem - t2 * 3;

        const float s3h = 0.8660254037844386f;
        float c0 = (t0 == 0) ? 1.0f : 0.5f;
        float s0 = (t0 == 0) ? 0.0f : ((t0 == 1) ? s3h : -s3h);
        float c1 = (t1 == 0) ? 1.0f : 0.5f;
        float s1 = (t1 == 0) ? 0.0f : ((t1 == 1) ? s3h : -s3h);
        float c2 = (t2 == 0) ? 1.0f : 0.5f;
        float s2 = (t2 == 0) ? 0.0f : ((t2 == 1) ? s3h : -s3h);
        float c3v = (t3 == 0) ? 1.0f : 0.5f;
        float s3v = (t3 == 0) ? 0.0f : ((t3 == 1) ? s3h : -s3h);

        const float* wq = (g == 0) ? wq_f : (g == 1) ? wq_i : (g == 2) ? wq_u : wq_o;
        float lc[NL * NQ], ls[NL * NQ];
        #pragma unroll
        for (int a = 0; a < NL * NQ; ++a) {
            float ang = wq[a] * 0.5f;
            lc[a] = __cosf(ang);
            ls[a] = __sinf(ang);
        }

        // init product state with (-i)^popcount phase
        float m01[4], m23[4];
        m01[0] = c0 * c1; m01[1] = c0 * s1; m01[2] = s0 * c1; m01[3] = s0 * s1;
        m23[0] = c2 * c3v; m23[1] = c2 * s3v; m23[2] = s2 * c3v; m23[3] = s2 * s3v;
        float ar[16], ai[16];
        #pragma unroll
        for (int b0 = 0; b0 < 2; ++b0)
        #pragma unroll
        for (int b1 = 0; b1 < 2; ++b1)
        #pragma unroll
        for (int b2 = 0; b2 < 2; ++b2)
        #pragma unroll
        for (int b3 = 0; b3 < 2; ++b3) {
            const int idx = (b0 << 3) | (b1 << 2) | (b2 << 1) | b3;
            const int pc  = (b0 + b1 + b2 + b3) & 3;
            float m = m01[(b0 << 1) | b1] * m23[(b2 << 1) | b3];
            float re, im;
            if (pc == 0)      { re =  m;   im = 0.0f; }
            else if (pc == 1) { re = 0.0f; im = -m;   }
            else if (pc == 2) { re = -m;   im = 0.0f; }
            else              { re = 0.0f; im =  m;   }
            ar[idx] = re; ai[idx] = im;
        }

        #pragma unroll
        for (int l = 0; l < NL; ++l) {
            RX_W(0, lc[l*4+0], ls[l*4+0]);
            RX_W(1, lc[l*4+1], ls[l*4+1]);
            RX_W(2, lc[l*4+2], ls[l*4+2]);
            RX_W(3, lc[l*4+3], ls[l*4+3]);
            CNOT_W(0, 1); CNOT_W(1, 2); CNOT_W(2, 3); CNOT_W(3, 0);
        }

        float e0 = 0.f, e1 = 0.f, e2 = 0.f, e3 = 0.f;
        #pragma unroll
        for (int idx = 0; idx < 16; ++idx) {
            float pv = fmaf(ar[idx], ar[idx], ai[idx] * ai[idx]);
            e0 += (idx & 8) ? -pv : pv;
            e1 += (idx & 4) ? -pv : pv;
            e2 += (idx & 2) ? -pv : pv;
            e3 += (idx & 1) ? -pv : pv;
        }
        sC[(g * 4 + 0) * 84 + p] = e0;
        sC[(g * 4 + 1) * 84 + p] = e1;
        sC[(g * 4 + 2) * 84 + p] = e2;
        sC[(g * 4 + 3) * 84 + p] = e3;
    }
    __syncthreads();

    // ---------------- P3: inverse transform per axis (values -> coeffs) -------
    TPASS(27); TPASS(9); TPASS(3); TPASS(1);

    // ---------------- P4: fold with w_out/b_out -> per-lane D[81] -------------
    float D[81];
    {
        const float wo0 = w_out[j * 4 + 0], wo1 = w_out[j * 4 + 1];
        const float wo2 = w_out[j * 4 + 2], wo3 = w_out[j * 4 + 3];
        const float* r0 = sC + (w * 4 + 0) * 84;
        const float* r1 = sC + (w * 4 + 1) * 84;
        const float* r2 = sC + (w * 4 + 2) * 84;
        const float* r3 = sC + (w * 4 + 3) * 84;
        #pragma unroll
        for (int q = 0; q < 20; ++q) {
            float4 a0 = *reinterpret_cast<const float4*>(r0 + 4 * q);
            float4 a1 = *reinterpret_cast<const float4*>(r1 + 4 * q);
            float4 a2 = *reinterpret_cast<const float4*>(r2 + 4 * q);
            float4 a3 = *reinterpret_cast<const float4*>(r3 + 4 * q);
            D[4*q+0] = fmaf(wo0,a0.x, fmaf(wo1,a1.x, fmaf(wo2,a2.x, wo3*a3.x)));
            D[4*q+1] = fmaf(wo0,a0.y, fmaf(wo1,a1.y, fmaf(wo2,a2.y, wo3*a3.y)));
            D[4*q+2] = fmaf(wo0,a0.z, fmaf(wo1,a1.z, fmaf(wo2,a2.z, wo3*a3.z)));
            D[4*q+3] = fmaf(wo0,a0.w, fmaf(wo1,a1.w, fmaf(wo2,a2.w, wo3*a3.w)));
        }
        D[80] = fmaf(wo0,r0[80], fmaf(wo1,r1[80], fmaf(wo2,r2[80], wo3*r3[80])));
        D[0] += b_out[j];
    }

    // ---------------- main recurrence -----------------------------------------
    float wh[HH], wfc[HH];
    #pragma unroll
    for (int k = 0; k < HH; ++k) { wh[k] = w_in[w * 40 + k]; wfc[k] = w_fc[k]; }

    const bool  isG  = (w == 2);
    const float inS  = isG ? 2.0f : 1.0f;
    const float outS = isG ? 2.0f : 1.0f;
    const float outB = isG ? -1.0f : 0.0f;

    // bpermute byte-addresses of the 8 column representatives (lane base32+4k)
    int hadr[HH];
    #pragma unroll
    for (int k = 0; k < HH; ++k) hadr[k] = (((lane & 32) + 4 * k) << 2);

    float hk[HH];
    #pragma unroll
    for (int k = 0; k < HH; ++k) hk[k] = 0.0f;
    float cc = 0.0f;

    float xwv = sXW[(half * 65 + 0) * 4 + w];

    for (int t = 0; t < TT; ++t) {
        float xwn = sXW[(half * 65 + t + 1) * 4 + w];   // prefetch (pad row at t=63)

        // y_w = xw + h.wh   (h replicated: local FMAs)
        float y = xwv;
        #pragma unroll
        for (int k = 0; k < HH; ++k) y = fmaf(hk[k], wh[k], y);

        // basis for all wires via quad broadcast (u_q,v_q live in-quad at pos q)
        float u = __cosf(y), v = __sinf(y);
        float u0 = QUAD_BCAST(u, 0x00), u1 = QUAD_BCAST(u, 0x55);
        float u2 = QUAD_BCAST(u, 0xAA), u3 = QUAD_BCAST(u, 0xFF);
        float v0 = QUAD_BCAST(v, 0x00), v1 = QUAD_BCAST(v, 0x55);
        float v2 = QUAD_BCAST(v, 0xAA), v3 = QUAD_BCAST(v, 0xFF);

        // factored 81-term contraction (80 FMA)
        float c3[27];
        #pragma unroll
        for (int i = 0; i < 27; ++i)
            c3[i] = fmaf(u3, D[3*i+1], fmaf(v3, D[3*i+2], D[3*i]));
        float c2[9];
        #pragma unroll
        for (int i = 0; i < 9; ++i)
            c2[i] = fmaf(u2, c3[3*i+1], fmaf(v2, c3[3*i+2], c3[3*i]));
        float c1[3];
        #pragma unroll
        for (int i = 0; i < 3; ++i)
            c1[i] = fmaf(u1, c2[3*i+1], fmaf(v1, c2[3*i+2], c2[3*i]));
        const float a = fmaf(u0, c1[1], fmaf(v0, c1[2], c1[0]));

        // activation
        const float sg  = 1.0f / (1.0f + __expf(-inS * a));
        const float act = fmaf(sg, outS, outB);

        // gather the quad's 4 gate values via DPP (VALU)
        const float fv = QUAD_BCAST(act, 0x00);
        const float iv = QUAD_BCAST(act, 0x55);
        const float gv = QUAD_BCAST(act, 0xAA);
        const float ov = QUAD_BCAST(act, 0xFF);

        // cell update for this lane's column j (replicated within quad)
        cc = fmaf(fv, cc, iv * gv);
        const float th = 2.0f / (1.0f + __expf(-2.0f * cc)) - 1.0f;
        const float hloc = ov * th;

        // collect all 8 columns' h (one parallel DS level)
        const int hb = __float_as_int(hloc);
        #pragma unroll
        for (int k = 0; k < HH; ++k)
            hk[k] = __int_as_float(__builtin_amdgcn_ds_bpermute(hadr[k], hb));

        xwv = xwn;
    }

    // out[elem] = h.w_fc + b_fc   (h already replicated on every lane)
    if ((lane & 31) == 0) {
        float r = b_fc[0];
        #pragma unroll
        for (int k = 0; k < HH; ++k) r = fmaf(hk[k], wfc[k], r);
        out[elem] = r;
    }
}

extern "C" void kernel_launch(void* const* d_in, const int* in_sizes, int n_in,
                              void* d_out, int out_size, void* d_ws, size_t ws_size,
                              hipStream_t stream) {
    const float* x     = (const float*)d_in[0];
    const float* w_in  = (const float*)d_in[1];
    const float* b_in  = (const float*)d_in[2];
    const float* w_out = (const float*)d_in[3];
    const float* b_out = (const float*)d_in[4];
    const float* wq_f  = (const float*)d_in[5];
    const float* wq_i  = (const float*)d_in[6];
    const float* wq_u  = (const float*)d_in[7];
    const float* wq_o  = (const float*)d_in[8];
    const float* w_fc  = (const float*)d_in[9];
    const float* b_fc  = (const float*)d_in[10];
    float* out = (float*)d_out;
    (void)in_sizes; (void)n_in; (void)out_size; (void)d_ws; (void)ws_size;

    qlstm_fused_kernel<<<BB / 2, 64, 0, stream>>>(x, w_in, b_in, w_out, b_out,
                                                  wq_f, wq_i, wq_u, wq_o,
                                                  w_fc, b_fc, out);
}

// Round 4
// 112.034 us; speedup vs baseline: 1.8177x; 1.0201x over previous
//
#include <hip/hip_runtime.h>
#include <math.h>

// QLSTM, single-kernel exact-polynomial formulation, 16 lanes/element.
// Lane = (gate w, unit-pair jj/jj+4); 4 elements per wave (row of 16 each).
// Loop-carried chain is DS-free: y-reduce via DPP row_ror adds, act gather
// and u/v broadcast via DPP quad_perm.  Polynomial D kept as float2 pairs
// (unit jj, unit jj+4) -> v_pk_fma_f32 tree (160 FMA in 80 insts), pinned
// in VGPRs via asm.

#define NQ 4
#define NL 2
#define BB 1024
#define TT 64
#define FF 32
#define HH 8

typedef float v2f __attribute__((ext_vector_type(2)));
#define FMA2(a, b, c) __builtin_elementwise_fma((a), (b), (c))

// ---- register statevector circuit macros (verified rounds 1-3) -----------
#define RX_W(wv, cc, ss) do {                                   \
    const int str_ = 8 >> (wv);                                 \
    _Pragma("unroll")                                           \
    for (int lo_ = 0; lo_ < 16; ++lo_) {                        \
      if ((lo_ & str_) == 0) {                                  \
        const int hi_ = lo_ | str_;                             \
        float a0r = ar[lo_], a0i = ai[lo_];                     \
        float a1r = ar[hi_], a1i = ai[hi_];                     \
        ar[lo_] = fmaf((cc), a0r,  (ss)*a1i);                   \
        ai[lo_] = fmaf((cc), a0i, -(ss)*a1r);                   \
        ar[hi_] = fmaf((cc), a1r,  (ss)*a0i);                   \
        ai[hi_] = fmaf((cc), a1i, -(ss)*a0r);                   \
      }                                                         \
    }                                                           \
} while (0)

#define CNOT_W(cw, tw) do {                                     \
    const int cb_ = 1 << (3-(cw));                              \
    const int tb_ = 1 << (3-(tw));                              \
    _Pragma("unroll")                                           \
    for (int ix_ = 0; ix_ < 16; ++ix_) {                        \
      if ((ix_ & cb_) && !(ix_ & tb_)) {                        \
        const int jx_ = ix_ | tb_;                              \
        float tr_ = ar[ix_]; ar[ix_] = ar[jx_]; ar[jx_] = tr_;  \
        float ti_ = ai[ix_]; ai[ix_] = ai[jx_]; ai[jx_] = ti_;  \
      }                                                         \
    }                                                           \
} while (0)

// DPP quad_perm broadcast of quad position (VALU cross-lane)
#define QUAD_BCAST(x, CTRL) \
    __int_as_float(__builtin_amdgcn_mov_dpp(__float_as_int(x), (CTRL), 0xf, 0xf, true))
// DPP row rotate (within 16-lane row)
#define ROW_ROR(x, N) \
    __int_as_float(__builtin_amdgcn_mov_dpp(__float_as_int(x), 0x120 + (N), 0xf, 0xf, true))

// in-place 3-point inverse transform along one axis (stride ST) of sC rows
#define TPASS(ST) do {                                                       \
    for (int i_ = threadIdx.x; i_ < 432; i_ += 64) {                         \
      int gw_ = i_ / 27; int r_ = i_ - gw_*27;                               \
      int hi_ = r_ / (ST); int lo_ = r_ - hi_*(ST);                          \
      float* row_ = sC + gw_*84; int p0_ = hi_*3*(ST) + lo_;                 \
      float f0_ = row_[p0_], f1_ = row_[p0_+(ST)], f2_ = row_[p0_+2*(ST)];   \
      row_[p0_]          = (f0_ + f1_ + f2_) * 0.3333333333333333f;          \
      row_[p0_+(ST)]     = (2.0f*f0_ - f1_ - f2_) * 0.3333333333333333f;     \
      row_[p0_+2*(ST)]   = (f1_ - f2_) * 0.5773502691896258f;                \
    }                                                                        \
    __syncthreads();                                                         \
} while (0)

__global__ __launch_bounds__(64, 1)
void qlstm16_kernel(const float* __restrict__ x,
                    const float* __restrict__ w_in,
                    const float* __restrict__ b_in,
                    const float* __restrict__ w_out,
                    const float* __restrict__ b_out,
                    const float* __restrict__ wq_f,
                    const float* __restrict__ wq_i,
                    const float* __restrict__ wq_u,
                    const float* __restrict__ wq_o,
                    const float* __restrict__ w_fc,
                    const float* __restrict__ b_fc,
                    float* __restrict__ out) {
    __shared__ float sC[16 * 84];                     // [g*4+w][coeff]
    __shared__ __align__(16) float sXW[4 * 65 * 4];   // [e][t][w], t padded

    const int lane = threadIdx.x;
    const int w    = lane & 3;          // gate id AND wire id for this lane
    const int jj   = (lane >> 2) & 3;   // unit pair base: units jj, jj+4
    const int q    = lane >> 4;         // element slot within wave (row)
    const int elem = blockIdx.x * 4 + q;

    // ---------------- P1: xw[e][t][w] = b_in[w] + x[e,t,:].w_in[w,8:] ------
    {
        const float b0 = b_in[0], b1 = b_in[1], b2 = b_in[2], b3 = b_in[3];
        #pragma unroll
        for (int r = 0; r < 4; ++r) {
            int slot = lane + 64 * r;          // 0..255
            int e = slot >> 6, t = slot & 63;
            const float* xr = x + ((size_t)(blockIdx.x * 4 + e) * TT + t) * FF;
            float a0 = b0, a1 = b1, a2 = b2, a3 = b3;
            #pragma unroll
            for (int k = 0; k < 8; ++k) {
                float4 xv = *reinterpret_cast<const float4*>(xr + 4 * k);
                const float* p0 = w_in + 0 * 40 + 8 + 4 * k;
                const float* p1 = w_in + 1 * 40 + 8 + 4 * k;
                const float* p2 = w_in + 2 * 40 + 8 + 4 * k;
                const float* p3 = w_in + 3 * 40 + 8 + 4 * k;
                a0 = fmaf(xv.x, p0[0], fmaf(xv.y, p0[1], fmaf(xv.z, p0[2], fmaf(xv.w, p0[3], a0))));
                a1 = fmaf(xv.x, p1[0], fmaf(xv.y, p1[1], fmaf(xv.z, p1[2], fmaf(xv.w, p1[3], a1))));
                a2 = fmaf(xv.x, p2[0], fmaf(xv.y, p2[1], fmaf(xv.z, p2[2], fmaf(xv.w, p2[3], a2))));
                a3 = fmaf(xv.x, p3[0], fmaf(xv.y, p3[1], fmaf(xv.z, p3[2], fmaf(xv.w, p3[3], a3))));
            }
            float4 st = {a0, a1, a2, a3};
            *reinterpret_cast<float4*>(sXW + (e * 65 + t) * 4) = st;
        }
    }

    // ---------------- P2: simulate circuit at 81 constant grid points ------
    for (int sidx = lane; sidx < 324; sidx += 64) {
        int g = sidx / 81;
        int p = sidx - g * 81;
        int t0 = p / 27; int rem = p - t0 * 27;
        int t1 = rem / 9; rem -= t1 * 9;
        int t2 = rem / 3; int t3 = rem - t2 * 3;

        const float s3h = 0.8660254037844386f;
        float c0 = (t0 == 0) ? 1.0f : 0.5f;
        float s0 = (t0 == 0) ? 0.0f : ((t0 == 1) ? s3h : -s3h);
        float c1 = (t1 == 0) ? 1.0f : 0.5f;
        float s1 = (t1 == 0) ? 0.0f : ((t1 == 1) ? s3h : -s3h);
        float c2 = (t2 == 0) ? 1.0f : 0.5f;
        float s2 = (t2 == 0) ? 0.0f : ((t2 == 1) ? s3h : -s3h);
        float c3v = (t3 == 0) ? 1.0f : 0.5f;
        float s3v = (t3 == 0) ? 0.0f : ((t3 == 1) ? s3h : -s3h);

        const float* wq = (g == 0) ? wq_f : (g == 1) ? wq_i : (g == 2) ? wq_u : wq_o;
        float lc[NL * NQ], ls[NL * NQ];
        #pragma unroll
        for (int a = 0; a < NL * NQ; ++a) {
            float ang = wq[a] * 0.5f;
            lc[a] = __cosf(ang);
            ls[a] = __sinf(ang);
        }

        float m01[4], m23[4];
        m01[0] = c0 * c1;  m01[1] = c0 * s1;  m01[2] = s0 * c1;  m01[3] = s0 * s1;
        m23[0] = c2 * c3v; m23[1] = c2 * s3v; m23[2] = s2 * c3v; m23[3] = s2 * s3v;
        float ar[16], ai[16];
        #pragma unroll
        for (int b0 = 0; b0 < 2; ++b0)
        #pragma unroll
        for (int b1 = 0; b1 < 2; ++b1)
        #pragma unroll
        for (int b2 = 0; b2 < 2; ++b2)
        #pragma unroll
        for (int b3 = 0; b3 < 2; ++b3) {
            const int idx = (b0 << 3) | (b1 << 2) | (b2 << 1) | b3;
            const int pc  = (b0 + b1 + b2 + b3) & 3;
            float m = m01[(b0 << 1) | b1] * m23[(b2 << 1) | b3];
            float re, im;
            if (pc == 0)      { re =  m;   im = 0.0f; }
            else if (pc == 1) { re = 0.0f; im = -m;   }
            else if (pc == 2) { re = -m;   im = 0.0f; }
            else              { re = 0.0f; im =  m;   }
            ar[idx] = re; ai[idx] = im;
        }

        #pragma unroll
        for (int l = 0; l < NL; ++l) {
            RX_W(0, lc[l*4+0], ls[l*4+0]);
            RX_W(1, lc[l*4+1], ls[l*4+1]);
            RX_W(2, lc[l*4+2], ls[l*4+2]);
            RX_W(3, lc[l*4+3], ls[l*4+3]);
            CNOT_W(0, 1); CNOT_W(1, 2); CNOT_W(2, 3); CNOT_W(3, 0);
        }

        float e0 = 0.f, e1 = 0.f, e2 = 0.f, e3 = 0.f;
        #pragma unroll
        for (int idx = 0; idx < 16; ++idx) {
            float pv = fmaf(ar[idx], ar[idx], ai[idx] * ai[idx]);
            e0 += (idx & 8) ? -pv : pv;
            e1 += (idx & 4) ? -pv : pv;
            e2 += (idx & 2) ? -pv : pv;
            e3 += (idx & 1) ? -pv : pv;
        }
        sC[(g * 4 + 0) * 84 + p] = e0;
        sC[(g * 4 + 1) * 84 + p] = e1;
        sC[(g * 4 + 2) * 84 + p] = e2;
        sC[(g * 4 + 3) * 84 + p] = e3;
    }
    __syncthreads();

    // ---------------- P3: inverse transform (values -> coefficients) -------
    TPASS(27); TPASS(9); TPASS(3); TPASS(1);

    // ---------------- P4: fold w_out/b_out -> per-lane paired Dp[81] -------
    v2f Dp[81];
    {
        const float xa0 = w_out[jj * 4 + 0],       xa1 = w_out[jj * 4 + 1];
        const float xa2 = w_out[jj * 4 + 2],       xa3 = w_out[jj * 4 + 3];
        const float xb0 = w_out[(jj + 4) * 4 + 0], xb1 = w_out[(jj + 4) * 4 + 1];
        const float xb2 = w_out[(jj + 4) * 4 + 2], xb3 = w_out[(jj + 4) * 4 + 3];
        const float* r0 = sC + (w * 4 + 0) * 84;
        const float* r1 = sC + (w * 4 + 1) * 84;
        const float* r2 = sC + (w * 4 + 2) * 84;
        const float* r3 = sC + (w * 4 + 3) * 84;
        #pragma unroll
        for (int i = 0; i < 81; ++i) {
            float e0 = r0[i], e1 = r1[i], e2 = r2[i], e3 = r3[i];
            float da = fmaf(xa0, e0, fmaf(xa1, e1, fmaf(xa2, e2, xa3 * e3)));
            float db = fmaf(xb0, e0, fmaf(xb1, e1, fmaf(xb2, e2, xb3 * e3)));
            Dp[i] = v2f{da, db};
        }
        Dp[0] += v2f{b_out[jj], b_out[jj + 4]};
    }
    // pin the 81 coefficient pairs in VGPRs; block sinking into the loop
    #pragma unroll
    for (int i = 0; i < 81; ++i) asm volatile("" : "+v"(Dp[i]));

    // ---------------- main recurrence --------------------------------------
    const float whA  = w_in[w * 40 + jj];
    const float whB  = w_in[w * 40 + jj + 4];
    const float wfcA = w_fc[jj];
    const float wfcB = w_fc[jj + 4];

    const bool  isG  = (w == 2);
    const float inS  = isG ? 2.0f : 1.0f;
    const float outS = isG ? 2.0f : 1.0f;
    const float outB = isG ? -1.0f : 0.0f;

    const float* sxw = sXW + q * 260 + w;    // (q*65 + t)*4 + w

    float ccA = 0.0f, ccB = 0.0f, hA = 0.0f, hB = 0.0f;
    float xwv = sxw[0];

    for (int t = 0; t < TT; ++t) {
        float xwn = sxw[4 * (t + 1)];        // prefetch (pad slot at t=63)

        // ---- y_w = xw + sum_k w_in[w,k] h_k  (DPP row reduce, no DS)
        float p = fmaf(hA, whA, hB * whB);
        float s = p + ROW_ROR(p, 4);
        s = s + ROW_ROR(s, 8);
        const float y = xwv + s;

        // ---- per-wire basis via quad broadcast
        const float u = __cosf(y), v = __sinf(y);
        const float u0s = QUAD_BCAST(u, 0x00), u1s = QUAD_BCAST(u, 0x55);
        const float u2s = QUAD_BCAST(u, 0xAA), u3s = QUAD_BCAST(u, 0xFF);
        const float v0s = QUAD_BCAST(v, 0x00), v1s = QUAD_BCAST(v, 0x55);
        const float v2s = QUAD_BCAST(v, 0xAA), v3s = QUAD_BCAST(v, 0xFF);
        const v2f ud0 = {u0s, u0s}, ud1 = {u1s, u1s}, ud2 = {u2s, u2s}, ud3 = {u3s, u3s};
        const v2f vd0 = {v0s, v0s}, vd1 = {v1s, v1s}, vd2 = {v2s, v2s}, vd3 = {v3s, v3s};

        // ---- packed 81-term contraction: 2 units in one v_pk_fma stream
        v2f c2[9];
        #pragma unroll
        for (int i = 0; i < 9; ++i) {
            v2f q0 = FMA2(ud3, Dp[9*i+1], FMA2(vd3, Dp[9*i+2], Dp[9*i+0]));
            v2f q1 = FMA2(ud3, Dp[9*i+4], FMA2(vd3, Dp[9*i+5], Dp[9*i+3]));
            v2f q2 = FMA2(ud3, Dp[9*i+7], FMA2(vd3, Dp[9*i+8], Dp[9*i+6]));
            c2[i] = FMA2(ud2, q1, FMA2(vd2, q2, q0));
        }
        v2f c1a = FMA2(ud1, c2[1], FMA2(vd1, c2[2], c2[0]));
        v2f c1b = FMA2(ud1, c2[4], FMA2(vd1, c2[5], c2[3]));
        v2f c1c = FMA2(ud1, c2[7], FMA2(vd1, c2[8], c2[6]));
        const v2f av = FMA2(ud0, c1b, FMA2(vd0, c1c, c1a));

        // ---- activations (sigmoid; tanh = 2*sig(2a)-1 for gate u)
        const float sgA = __builtin_amdgcn_rcpf(1.0f + __expf(-inS * av.x));
        const float sgB = __builtin_amdgcn_rcpf(1.0f + __expf(-inS * av.y));
        const float actA = fmaf(sgA, outS, outB);
        const float actB = fmaf(sgB, outS, outB);

        // ---- gather the quad's 4 gate values (DPP)
        const float fA = QUAD_BCAST(actA, 0x00), iA = QUAD_BCAST(actA, 0x55);
        const float gA = QUAD_BCAST(actA, 0xAA), oA = QUAD_BCAST(actA, 0xFF);
        const float fB = QUAD_BCAST(actB, 0x00), iB = QUAD_BCAST(actB, 0x55);
        const float gB = QUAD_BCAST(actB, 0xAA), oB = QUAD_BCAST(actB, 0xFF);

        // ---- cell updates (units jj, jj+4; replicated within quad)
        ccA = fmaf(fA, ccA, iA * gA);
        const float thA = fmaf(2.0f, __builtin_amdgcn_rcpf(1.0f + __expf(-2.0f * ccA)), -1.0f);
        hA = oA * thA;
        ccB = fmaf(fB, ccB, iB * gB);
        const float thB = fmaf(2.0f, __builtin_amdgcn_rcpf(1.0f + __expf(-2.0f * ccB)), -1.0f);
        hB = oB * thB;

        xwv = xwn;
    }

    // ---- out[elem] = h.w_fc + b_fc  (DPP row reduce)
    float pf = fmaf(hA, wfcA, hB * wfcB);
    float sf = pf + ROW_ROR(pf, 4);
    sf = sf + ROW_ROR(sf, 8);
    if ((lane & 15) == 0) out[elem] = sf + b_fc[0];
}

extern "C" void kernel_launch(void* const* d_in, const int* in_sizes, int n_in,
                              void* d_out, int out_size, void* d_ws, size_t ws_size,
                              hipStream_t stream) {
    const float* x     = (const float*)d_in[0];
    const float* w_in  = (const float*)d_in[1];
    const float* b_in  = (const float*)d_in[2];
    const float* w_out = (const float*)d_in[3];
    const float* b_out = (const float*)d_in[4];
    const float* wq_f  = (const float*)d_in[5];
    const float* wq_i  = (const float*)d_in[6];
    const float* wq_u  = (const float*)d_in[7];
    const float* wq_o  = (const float*)d_in[8];
    const float* w_fc  = (const float*)d_in[9];
    const float* b_fc  = (const float*)d_in[10];
    float* out = (float*)d_out;
    (void)in_sizes; (void)n_in; (void)out_size; (void)d_ws; (void)ws_size;

    qlstm16_kernel<<<BB / 4, 64, 0, stream>>>(x, w_in, b_in, w_out, b_out,
                                              wq_f, wq_i, wq_u, wq_o,
                                              w_fc, b_fc, out);
}

// Round 5
// 109.055 us; speedup vs baseline: 1.8674x; 1.0273x over previous
//
#include <hip/hip_runtime.h>
#include <math.h>

// QLSTM, single-kernel exact-polynomial formulation, 32 lanes/element.
// Lane = (gate w [bits 0-1], hidden unit j [bits 2-4], element e [bit 5]).
// Each lane owns ONE unit -> D[81] scalar coefficients stay VGPR-resident
// (the round-4 float2 variant needed 162 regs and fell off the residency
// cliff into AGPR shuffling).  Per step: y-reduce = pair FMA + 2 row-DPP
// adds + 1 ds_swizzle xor16; basis + act gather via quad-DPP; 80 scalar
// FMA tree; cell update local.

#define NQ 4
#define NL 2
#define BB 1024
#define TT 64
#define FF 32
#define HH 8

// ---- register statevector circuit macros (verified rounds 1-4) -----------
#define RX_W(wv, cc, ss) do {                                   \
    const int str_ = 8 >> (wv);                                 \
    _Pragma("unroll")                                           \
    for (int lo_ = 0; lo_ < 16; ++lo_) {                        \
      if ((lo_ & str_) == 0) {                                  \
        const int hi_ = lo_ | str_;                             \
        float a0r = ar[lo_], a0i = ai[lo_];                     \
        float a1r = ar[hi_], a1i = ai[hi_];                     \
        ar[lo_] = fmaf((cc), a0r,  (ss)*a1i);                   \
        ai[lo_] = fmaf((cc), a0i, -(ss)*a1r);                   \
        ar[hi_] = fmaf((cc), a1r,  (ss)*a0i);                   \
        ai[hi_] = fmaf((cc), a1i, -(ss)*a0r);                   \
      }                                                         \
    }                                                           \
} while (0)

#define CNOT_W(cw, tw) do {                                     \
    const int cb_ = 1 << (3-(cw));                              \
    const int tb_ = 1 << (3-(tw));                              \
    _Pragma("unroll")                                           \
    for (int ix_ = 0; ix_ < 16; ++ix_) {                        \
      if ((ix_ & cb_) && !(ix_ & tb_)) {                        \
        const int jx_ = ix_ | tb_;                              \
        float tr_ = ar[ix_]; ar[ix_] = ar[jx_]; ar[jx_] = tr_;  \
        float ti_ = ai[ix_]; ai[ix_] = ai[jx_]; ai[jx_] = ti_;  \
      }                                                         \
    }                                                           \
} while (0)

// DPP quad_perm broadcast of quad position (VALU cross-lane)
#define QUAD_BCAST(x, CTRL) \
    __int_as_float(__builtin_amdgcn_mov_dpp(__float_as_int(x), (CTRL), 0xf, 0xf, true))
// DPP row rotate (within 16-lane row)
#define ROW_ROR(x, N) \
    __int_as_float(__builtin_amdgcn_mov_dpp(__float_as_int(x), 0x120 + (N), 0xf, 0xf, true))
// ds_swizzle lane ^ 16 (within 32-lane groups)
#define SWZ_X16(x) \
    __int_as_float(__builtin_amdgcn_ds_swizzle(__float_as_int(x), 0x401F))

// in-place 3-point inverse transform along one axis (stride ST) of sC rows
#define TPASS(ST) do {                                                       \
    for (int i_ = threadIdx.x; i_ < 432; i_ += 64) {                         \
      int gw_ = i_ / 27; int r_ = i_ - gw_*27;                               \
      int hi_ = r_ / (ST); int lo_ = r_ - hi_*(ST);                          \
      float* row_ = sC + gw_*84; int p0_ = hi_*3*(ST) + lo_;                 \
      float f0_ = row_[p0_], f1_ = row_[p0_+(ST)], f2_ = row_[p0_+2*(ST)];   \
      row_[p0_]          = (f0_ + f1_ + f2_) * 0.3333333333333333f;          \
      row_[p0_+(ST)]     = (2.0f*f0_ - f1_ - f2_) * 0.3333333333333333f;     \
      row_[p0_+2*(ST)]   = (f1_ - f2_) * 0.5773502691896258f;                \
    }                                                                        \
    __syncthreads();                                                         \
} while (0)

__global__ __launch_bounds__(64, 1)
void qlstm32_kernel(const float* __restrict__ x,
                    const float* __restrict__ w_in,
                    const float* __restrict__ b_in,
                    const float* __restrict__ w_out,
                    const float* __restrict__ b_out,
                    const float* __restrict__ wq_f,
                    const float* __restrict__ wq_i,
                    const float* __restrict__ wq_u,
                    const float* __restrict__ wq_o,
                    const float* __restrict__ w_fc,
                    const float* __restrict__ b_fc,
                    float* __restrict__ out) {
    __shared__ float sC[16 * 84];                     // [g*4+wire][coeff]
    __shared__ __align__(16) float sXW[2 * 65 * 4];   // [e][t][w], t padded

    const int lane = threadIdx.x;
    const int w    = lane & 3;          // gate id AND wire id for this lane
    const int j    = (lane >> 2) & 7;   // hidden unit owned by this lane
    const int e    = lane >> 5;         // element slot (2 per block)

    // ---------------- P1: xw[e][t][w] = b_in[w] + x[elem,t,:].w_in[w,8:] ---
    {
        const float b0 = b_in[0], b1 = b_in[1], b2 = b_in[2], b3 = b_in[3];
        #pragma unroll
        for (int r = 0; r < 8; ++r) {
            int slot = lane + 64 * r;          // 0..511 = e(1) t(6) w(2)
            int ee = slot >> 8;
            int tt = (slot >> 2) & 63;
            int ww = slot & 3;
            const float* xr = x + ((size_t)(blockIdx.x * 2 + ee) * TT + tt) * FF;
            float bb = (ww == 0) ? b0 : (ww == 1) ? b1 : (ww == 2) ? b2 : b3;
            const float* wrow = w_in + ww * 40 + 8;
            float acc = bb;
            #pragma unroll
            for (int k = 0; k < 8; ++k) {
                float4 xv = *reinterpret_cast<const float4*>(xr + 4 * k);
                acc = fmaf(xv.x, wrow[4*k+0],
                      fmaf(xv.y, wrow[4*k+1],
                      fmaf(xv.z, wrow[4*k+2],
                      fmaf(xv.w, wrow[4*k+3], acc))));
            }
            sXW[(ee * 65 + tt) * 4 + ww] = acc;
        }
    }

    // ---------------- P2: simulate circuit at 81 constant grid points ------
    for (int sidx = lane; sidx < 324; sidx += 64) {
        int g = sidx / 81;
        int p = sidx - g * 81;
        int t0 = p / 27; int rem = p - t0 * 27;
        int t1 = rem / 9; rem -= t1 * 9;
        int t2 = rem / 3; int t3 = rem - t2 * 3;

        const float s3h = 0.8660254037844386f;
        float c0 = (t0 == 0) ? 1.0f : 0.5f;
        float s0 = (t0 == 0) ? 0.0f : ((t0 == 1) ? s3h : -s3h);
        float c1 = (t1 == 0) ? 1.0f : 0.5f;
        float s1 = (t1 == 0) ? 0.0f : ((t1 == 1) ? s3h : -s3h);
        float c2 = (t2 == 0) ? 1.0f : 0.5f;
        float s2 = (t2 == 0) ? 0.0f : ((t2 == 1) ? s3h : -s3h);
        float c3v = (t3 == 0) ? 1.0f : 0.5f;
        float s3v = (t3 == 0) ? 0.0f : ((t3 == 1) ? s3h : -s3h);

        const float* wq = (g == 0) ? wq_f : (g == 1) ? wq_i : (g == 2) ? wq_u : wq_o;
        float lc[NL * NQ], ls[NL * NQ];
        #pragma unroll
        for (int a = 0; a < NL * NQ; ++a) {
            float ang = wq[a] * 0.5f;
            lc[a] = __cosf(ang);
            ls[a] = __sinf(ang);
        }

        float m01[4], m23[4];
        m01[0] = c0 * c1;  m01[1] = c0 * s1;  m01[2] = s0 * c1;  m01[3] = s0 * s1;
        m23[0] = c2 * c3v; m23[1] = c2 * s3v; m23[2] = s2 * c3v; m23[3] = s2 * s3v;
        float ar[16], ai[16];
        #pragma unroll
        for (int b0 = 0; b0 < 2; ++b0)
        #pragma unroll
        for (int b1 = 0; b1 < 2; ++b1)
        #pragma unroll
        for (int b2 = 0; b2 < 2; ++b2)
        #pragma unroll
        for (int b3 = 0; b3 < 2; ++b3) {
            const int idx = (b0 << 3) | (b1 << 2) | (b2 << 1) | b3;
            const int pc  = (b0 + b1 + b2 + b3) & 3;
            float m = m01[(b0 << 1) | b1] * m23[(b2 << 1) | b3];
            float re, im;
            if (pc == 0)      { re =  m;   im = 0.0f; }
            else if (pc == 1) { re = 0.0f; im = -m;   }
            else if (pc == 2) { re = -m;   im = 0.0f; }
            else              { re = 0.0f; im =  m;   }
            ar[idx] = re; ai[idx] = im;
        }

        #pragma unroll
        for (int l = 0; l < NL; ++l) {
            RX_W(0, lc[l*4+0], ls[l*4+0]);
            RX_W(1, lc[l*4+1], ls[l*4+1]);
            RX_W(2, lc[l*4+2], ls[l*4+2]);
            RX_W(3, lc[l*4+3], ls[l*4+3]);
            CNOT_W(0, 1); CNOT_W(1, 2); CNOT_W(2, 3); CNOT_W(3, 0);
        }

        float e0 = 0.f, e1 = 0.f, e2 = 0.f, e3 = 0.f;
        #pragma unroll
        for (int idx = 0; idx < 16; ++idx) {
            float pv = fmaf(ar[idx], ar[idx], ai[idx] * ai[idx]);
            e0 += (idx & 8) ? -pv : pv;
            e1 += (idx & 4) ? -pv : pv;
            e2 += (idx & 2) ? -pv : pv;
            e3 += (idx & 1) ? -pv : pv;
        }
        sC[(g * 4 + 0) * 84 + p] = e0;
        sC[(g * 4 + 1) * 84 + p] = e1;
        sC[(g * 4 + 2) * 84 + p] = e2;
        sC[(g * 4 + 3) * 84 + p] = e3;
    }
    __syncthreads();

    // ---------------- P3: inverse transform (values -> coefficients) -------
    TPASS(27); TPASS(9); TPASS(3); TPASS(1);

    // ---------------- P4: fold w_out/b_out -> per-lane scalar D[81] --------
    float D[81];
    {
        const float x0 = w_out[j * 4 + 0], x1 = w_out[j * 4 + 1];
        const float x2 = w_out[j * 4 + 2], x3 = w_out[j * 4 + 3];
        const float* r0 = sC + (w * 4 + 0) * 84;
        const float* r1 = sC + (w * 4 + 1) * 84;
        const float* r2 = sC + (w * 4 + 2) * 84;
        const float* r3 = sC + (w * 4 + 3) * 84;
        #pragma unroll
        for (int i = 0; i < 81; ++i)
            D[i] = fmaf(x0, r0[i], fmaf(x1, r1[i], fmaf(x2, r2[i], x3 * r3[i])));
        D[0] += b_out[j];
    }
    // pin coefficients in arch VGPRs; block sinking/remat into the loop
    #pragma unroll
    for (int i = 0; i < 81; ++i) asm volatile("" : "+v"(D[i]));

    // ---------------- main recurrence --------------------------------------
    const float wh  = w_in[w * 40 + j];   // y_w contribution of unit j
    const float wfc = w_fc[j];

    const bool  isG  = (w == 2);
    const float inS  = isG ? 2.0f : 1.0f;
    const float outS = isG ? 2.0f : 1.0f;
    const float outB = isG ? -1.0f : 0.0f;

    const float* sxw = sXW + e * 260 + w;    // (e*65 + t)*4 + w

    float cc = 0.0f, hh = 0.0f;              // unit j state (replicated x4 w)
    float xwv = sxw[0];

    for (int t = 0; t < TT; ++t) {
        float xwn = sxw[4 * (t + 1)];        // prefetch (pad slot at t=63)

        // ---- y_w = xw + sum_j w_in[w,j] h_j : row-DPP (4 j) + xor16 (8 j)
        float p = hh * wh;
        float s = p + ROW_ROR(p, 4);
        s = s + ROW_ROR(s, 8);
        s = s + SWZ_X16(s);
        const float y = xwv + s;

        // ---- per-wire basis via quad broadcast
        const float u = __cosf(y), v = __sinf(y);
        const float u0 = QUAD_BCAST(u, 0x00), u1 = QUAD_BCAST(u, 0x55);
        const float u2 = QUAD_BCAST(u, 0xAA), u3 = QUAD_BCAST(u, 0xFF);
        const float v0 = QUAD_BCAST(v, 0x00), v1 = QUAD_BCAST(v, 0x55);
        const float v2 = QUAD_BCAST(v, 0xAA), v3 = QUAD_BCAST(v, 0xFF);

        // ---- scalar 81-term factored contraction (80 FMA)
        float c3[27];
        #pragma unroll
        for (int i = 0; i < 27; ++i)
            c3[i] = fmaf(u3, D[3*i+1], fmaf(v3, D[3*i+2], D[3*i]));
        float c2[9];
        #pragma unroll
        for (int i = 0; i < 9; ++i)
            c2[i] = fmaf(u2, c3[3*i+1], fmaf(v2, c3[3*i+2], c3[3*i]));
        float c1[3];
        #pragma unroll
        for (int i = 0; i < 3; ++i)
            c1[i] = fmaf(u1, c2[3*i+1], fmaf(v1, c2[3*i+2], c2[3*i]));
        const float a = fmaf(u0, c1[1], fmaf(v0, c1[2], c1[0]));

        // ---- activation (sigmoid; tanh = 2*sig(2a)-1 for gate u)
        const float sg  = __builtin_amdgcn_rcpf(1.0f + __expf(-inS * a));
        const float act = fmaf(sg, outS, outB);

        // ---- gather the quad's 4 gate values (DPP)
        const float fv = QUAD_BCAST(act, 0x00), iv = QUAD_BCAST(act, 0x55);
        const float gv = QUAD_BCAST(act, 0xAA), ov = QUAD_BCAST(act, 0xFF);

        // ---- cell update for unit j
        cc = fmaf(fv, cc, iv * gv);
        const float th = fmaf(2.0f, __builtin_amdgcn_rcpf(1.0f + __expf(-2.0f * cc)), -1.0f);
        hh = ov * th;

        xwv = xwn;
    }

    // ---- out[elem] = h.w_fc + b_fc  (row-DPP + xor16 reduce over j)
    float pf = hh * wfc;
    float sf = pf + ROW_ROR(pf, 4);
    sf = sf + ROW_ROR(sf, 8);
    sf = sf + SWZ_X16(sf);
    if ((lane & 31) == 0) out[blockIdx.x * 2 + e] = sf + b_fc[0];
}

extern "C" void kernel_launch(void* const* d_in, const int* in_sizes, int n_in,
                              void* d_out, int out_size, void* d_ws, size_t ws_size,
                              hipStream_t stream) {
    const float* x     = (const float*)d_in[0];
    const float* w_in  = (const float*)d_in[1];
    const float* b_in  = (const float*)d_in[2];
    const float* w_out = (const float*)d_in[3];
    const float* b_out = (const float*)d_in[4];
    const float* wq_f  = (const float*)d_in[5];
    const float* wq_i  = (const float*)d_in[6];
    const float* wq_u  = (const float*)d_in[7];
    const float* wq_o  = (const float*)d_in[8];
    const float* w_fc  = (const float*)d_in[9];
    const float* b_fc  = (const float*)d_in[10];
    float* out = (float*)d_out;
    (void)in_sizes; (void)n_in; (void)out_size; (void)d_ws; (void)ws_size;

    qlstm32_kernel<<<BB / 2, 64, 0, stream>>>(x, w_in, b_in, w_out, b_out,
                                              wq_f, wq_i, wq_u, wq_o,
                                              w_fc, b_fc, out);
}

// Round 6
// 105.012 us; speedup vs baseline: 1.9393x; 1.0385x over previous
//
#include <hip/hip_runtime.h>
#include <math.h>

// QLSTM, single-kernel exact-polynomial formulation, 32 lanes/element.
// Lane = (gate/wire w [bits 0-1], hidden unit j [bits 2-4], element e [bit 5]).
// Round-6 changes vs round-5:
//  * lane^16 exchange via gfx950 v_permlane16_swap (VALU) -- the loop body now
//    contains ZERO chain DS ops (ds_swizzle + its lgkmcnt(0) drain removed).
//  * level-3 of the 81-term tree packed as v_pk_fma_f32 over adjacent coeff
//    pairs: same 81 VGPRs of coefficients (no residency cliff), 54 fewer
//    issue cycles per step.

#define NQ 4
#define NL 2
#define BB 1024
#define TT 64
#define FF 32
#define HH 8

typedef float v2f __attribute__((ext_vector_type(2)));
typedef unsigned uv2 __attribute__((ext_vector_type(2)));
#define FMA2(a, b, c) __builtin_elementwise_fma((a), (b), (c))

// ---- register statevector circuit macros (verified rounds 1-5) -----------
#define RX_W(wv, cc, ss) do {                                   \
    const int str_ = 8 >> (wv);                                 \
    _Pragma("unroll")                                           \
    for (int lo_ = 0; lo_ < 16; ++lo_) {                        \
      if ((lo_ & str_) == 0) {                                  \
        const int hi_ = lo_ | str_;                             \
        float a0r = ar[lo_], a0i = ai[lo_];                     \
        float a1r = ar[hi_], a1i = ai[hi_];                     \
        ar[lo_] = fmaf((cc), a0r,  (ss)*a1i);                   \
        ai[lo_] = fmaf((cc), a0i, -(ss)*a1r);                   \
        ar[hi_] = fmaf((cc), a1r,  (ss)*a0i);                   \
        ai[hi_] = fmaf((cc), a1i, -(ss)*a0r);                   \
      }                                                         \
    }                                                           \
} while (0)

#define CNOT_W(cw, tw) do {                                     \
    const int cb_ = 1 << (3-(cw));                              \
    const int tb_ = 1 << (3-(tw));                              \
    _Pragma("unroll")                                           \
    for (int ix_ = 0; ix_ < 16; ++ix_) {                        \
      if ((ix_ & cb_) && !(ix_ & tb_)) {                        \
        const int jx_ = ix_ | tb_;                              \
        float tr_ = ar[ix_]; ar[ix_] = ar[jx_]; ar[jx_] = tr_;  \
        float ti_ = ai[ix_]; ai[ix_] = ai[jx_]; ai[jx_] = ti_;  \
      }                                                         \
    }                                                           \
} while (0)

// DPP quad_perm broadcast of quad position (VALU cross-lane)
#define QUAD_BCAST(x, CTRL) \
    __int_as_float(__builtin_amdgcn_mov_dpp(__float_as_int(x), (CTRL), 0xf, 0xf, true))
// DPP row rotate (within 16-lane row)
#define ROW_ROR(x, N) \
    __int_as_float(__builtin_amdgcn_mov_dpp(__float_as_int(x), 0x120 + (N), 0xf, 0xf, true))
// ds_swizzle lane ^ 16 (epilogue only / fallback)
#define SWZ_X16(x) \
    __int_as_float(__builtin_amdgcn_ds_swizzle(__float_as_int(x), 0x401F))

// lane^16 value exchange. gfx950: v_permlane16_swap_b32 (VALU).  With
// a=b=s the swap gives: newA.row{1,3} = s.row{0,2}, newB.row{0,2} = s.row{1,3};
// even-row lanes read .y, odd-row lanes read .x  ->  s from lane^16.
#if __has_builtin(__builtin_amdgcn_permlane16_swap)
__device__ __forceinline__ float permx16(float s, int lane) {
    uv2 r = __builtin_amdgcn_permlane16_swap(__builtin_bit_cast(unsigned, s),
                                             __builtin_bit_cast(unsigned, s),
                                             false, false);
    unsigned pick = (lane & 16) ? r.x : r.y;
    return __builtin_bit_cast(float, pick);
}
#else
__device__ __forceinline__ float permx16(float s, int lane) {
    (void)lane;
    return SWZ_X16(s);
}
#endif

// in-place 3-point inverse transform along one axis (stride ST) of sC rows
#define TPASS(ST) do {                                                       \
    for (int i_ = threadIdx.x; i_ < 432; i_ += 64) {                         \
      int gw_ = i_ / 27; int r_ = i_ - gw_*27;                               \
      int hi_ = r_ / (ST); int lo_ = r_ - hi_*(ST);                          \
      float* row_ = sC + gw_*84; int p0_ = hi_*3*(ST) + lo_;                 \
      float f0_ = row_[p0_], f1_ = row_[p0_+(ST)], f2_ = row_[p0_+2*(ST)];   \
      row_[p0_]          = (f0_ + f1_ + f2_) * 0.3333333333333333f;          \
      row_[p0_+(ST)]     = (2.0f*f0_ - f1_ - f2_) * 0.3333333333333333f;     \
      row_[p0_+2*(ST)]   = (f1_ - f2_) * 0.5773502691896258f;                \
    }                                                                        \
    __syncthreads();                                                         \
} while (0)

// c3 accessor over packed pairs (k compile-time constant after unroll)
#define C3V(k) ((k) == 26 ? c3t : (((k) & 1) ? cp[(k) >> 1].y : cp[(k) >> 1].x))

__global__ __launch_bounds__(64, 1)
void qlstm32p_kernel(const float* __restrict__ x,
                     const float* __restrict__ w_in,
                     const float* __restrict__ b_in,
                     const float* __restrict__ w_out,
                     const float* __restrict__ b_out,
                     const float* __restrict__ wq_f,
                     const float* __restrict__ wq_i,
                     const float* __restrict__ wq_u,
                     const float* __restrict__ wq_o,
                     const float* __restrict__ w_fc,
                     const float* __restrict__ b_fc,
                     float* __restrict__ out) {
    __shared__ float sC[16 * 84];                     // [g*4+wire][coeff]
    __shared__ __align__(16) float sXW[2 * 65 * 4];   // [e][t][w], t padded

    const int lane = threadIdx.x;
    const int w    = lane & 3;          // gate id AND wire id for this lane
    const int j    = (lane >> 2) & 7;   // hidden unit owned by this lane
    const int e    = lane >> 5;         // element slot (2 per block)

    // ---------------- P1: xw[e][t][w] = b_in[w] + x[elem,t,:].w_in[w,8:] ---
    {
        const float b0 = b_in[0], b1 = b_in[1], b2 = b_in[2], b3 = b_in[3];
        #pragma unroll
        for (int r = 0; r < 8; ++r) {
            int slot = lane + 64 * r;          // 0..511 = e(1) t(6) w(2)
            int ee = slot >> 8;
            int tt = (slot >> 2) & 63;
            int ww = slot & 3;
            const float* xr = x + ((size_t)(blockIdx.x * 2 + ee) * TT + tt) * FF;
            float bb = (ww == 0) ? b0 : (ww == 1) ? b1 : (ww == 2) ? b2 : b3;
            const float* wrow = w_in + ww * 40 + 8;
            float acc = bb;
            #pragma unroll
            for (int k = 0; k < 8; ++k) {
                float4 xv = *reinterpret_cast<const float4*>(xr + 4 * k);
                acc = fmaf(xv.x, wrow[4*k+0],
                      fmaf(xv.y, wrow[4*k+1],
                      fmaf(xv.z, wrow[4*k+2],
                      fmaf(xv.w, wrow[4*k+3], acc))));
            }
            sXW[(ee * 65 + tt) * 4 + ww] = acc;
        }
    }

    // ---------------- P2: simulate circuit at 81 constant grid points ------
    for (int sidx = lane; sidx < 324; sidx += 64) {
        int g = sidx / 81;
        int p = sidx - g * 81;
        int t0 = p / 27; int rem = p - t0 * 27;
        int t1 = rem / 9; rem -= t1 * 9;
        int t2 = rem / 3; int t3 = rem - t2 * 3;

        const float s3h = 0.8660254037844386f;
        float c0 = (t0 == 0) ? 1.0f : 0.5f;
        float s0 = (t0 == 0) ? 0.0f : ((t0 == 1) ? s3h : -s3h);
        float c1 = (t1 == 0) ? 1.0f : 0.5f;
        float s1 = (t1 == 0) ? 0.0f : ((t1 == 1) ? s3h : -s3h);
        float c2 = (t2 == 0) ? 1.0f : 0.5f;
        float s2 = (t2 == 0) ? 0.0f : ((t2 == 1) ? s3h : -s3h);
        float c3v = (t3 == 0) ? 1.0f : 0.5f;
        float s3v = (t3 == 0) ? 0.0f : ((t3 == 1) ? s3h : -s3h);

        const float* wq = (g == 0) ? wq_f : (g == 1) ? wq_i : (g == 2) ? wq_u : wq_o;
        float lc[NL * NQ], ls[NL * NQ];
        #pragma unroll
        for (int a = 0; a < NL * NQ; ++a) {
            float ang = wq[a] * 0.5f;
            lc[a] = __cosf(ang);
            ls[a] = __sinf(ang);
        }

        float m01[4], m23[4];
        m01[0] = c0 * c1;  m01[1] = c0 * s1;  m01[2] = s0 * c1;  m01[3] = s0 * s1;
        m23[0] = c2 * c3v; m23[1] = c2 * s3v; m23[2] = s2 * c3v; m23[3] = s2 * s3v;
        float ar[16], ai[16];
        #pragma unroll
        for (int b0 = 0; b0 < 2; ++b0)
        #pragma unroll
        for (int b1 = 0; b1 < 2; ++b1)
        #pragma unroll
        for (int b2 = 0; b2 < 2; ++b2)
        #pragma unroll
        for (int b3 = 0; b3 < 2; ++b3) {
            const int idx = (b0 << 3) | (b1 << 2) | (b2 << 1) | b3;
            const int pc  = (b0 + b1 + b2 + b3) & 3;
            float m = m01[(b0 << 1) | b1] * m23[(b2 << 1) | b3];
            float re, im;
            if (pc == 0)      { re =  m;   im = 0.0f; }
            else if (pc == 1) { re = 0.0f; im = -m;   }
            else if (pc == 2) { re = -m;   im = 0.0f; }
            else              { re = 0.0f; im =  m;   }
            ar[idx] = re; ai[idx] = im;
        }

        #pragma unroll
        for (int l = 0; l < NL; ++l) {
            RX_W(0, lc[l*4+0], ls[l*4+0]);
            RX_W(1, lc[l*4+1], ls[l*4+1]);
            RX_W(2, lc[l*4+2], ls[l*4+2]);
            RX_W(3, lc[l*4+3], ls[l*4+3]);
            CNOT_W(0, 1); CNOT_W(1, 2); CNOT_W(2, 3); CNOT_W(3, 0);
        }

        float e0 = 0.f, e1 = 0.f, e2 = 0.f, e3 = 0.f;
        #pragma unroll
        for (int idx = 0; idx < 16; ++idx) {
            float pv = fmaf(ar[idx], ar[idx], ai[idx] * ai[idx]);
            e0 += (idx & 8) ? -pv : pv;
            e1 += (idx & 4) ? -pv : pv;
            e2 += (idx & 2) ? -pv : pv;
            e3 += (idx & 1) ? -pv : pv;
        }
        sC[(g * 4 + 0) * 84 + p] = e0;
        sC[(g * 4 + 1) * 84 + p] = e1;
        sC[(g * 4 + 2) * 84 + p] = e2;
        sC[(g * 4 + 3) * 84 + p] = e3;
    }
    __syncthreads();

    // ---------------- P3: inverse transform (values -> coefficients) -------
    TPASS(27); TPASS(9); TPASS(3); TPASS(1);

    // ---------------- P4: fold w_out/b_out -> per-lane packed coefficients --
    // Layout: pair p covers c3 indices 2p,2p+1 = D[6p..6p+5]:
    //   E0[p]={D[6p],D[6p+3]}, E1[p]={D[6p+1],D[6p+4]}, E2[p]={D[6p+2],D[6p+5]}
    // tail: e0s,e1s,e2s = D[78..80].  Total 81 VGPRs of coefficients.
    v2f E0[13], E1[13], E2[13];
    float e0s, e1s, e2s;
    {
        const float x0 = w_out[j * 4 + 0], x1 = w_out[j * 4 + 1];
        const float x2 = w_out[j * 4 + 2], x3 = w_out[j * 4 + 3];
        const float bo = b_out[j];
        const float* r0 = sC + (w * 4 + 0) * 84;
        const float* r1 = sC + (w * 4 + 1) * 84;
        const float* r2 = sC + (w * 4 + 2) * 84;
        const float* r3 = sC + (w * 4 + 3) * 84;
        #define DVAL(i) (fmaf(x0, r0[(i)], fmaf(x1, r1[(i)], fmaf(x2, r2[(i)], x3 * r3[(i)]))) \
                         + (((i) == 0) ? bo : 0.0f))
        #pragma unroll
        for (int p = 0; p < 13; ++p) {
            E0[p] = v2f{DVAL(6*p + 0), DVAL(6*p + 3)};
            E1[p] = v2f{DVAL(6*p + 1), DVAL(6*p + 4)};
            E2[p] = v2f{DVAL(6*p + 2), DVAL(6*p + 5)};
        }
        e0s = DVAL(78); e1s = DVAL(79); e2s = DVAL(80);
        #undef DVAL
    }
    // pin coefficients in VGPRs; block sinking/remat into the loop
    #pragma unroll
    for (int i = 0; i < 13; ++i)
        asm volatile("" : "+v"(E0[i]), "+v"(E1[i]), "+v"(E2[i]));
    asm volatile("" : "+v"(e0s), "+v"(e1s), "+v"(e2s));

    // ---------------- main recurrence --------------------------------------
    const float wh  = w_in[w * 40 + j];   // y_w contribution of unit j
    const float wfc = w_fc[j];

    const bool  isG  = (w == 2);
    const float inS  = isG ? 2.0f : 1.0f;
    const float outS = isG ? 2.0f : 1.0f;
    const float outB = isG ? -1.0f : 0.0f;

    const float* sxw = sXW + e * 260 + w;    // (e*65 + t)*4 + w

    float cc = 0.0f, hh = 0.0f;              // unit j state (replicated x4 w)
    float xwv = sxw[0];

    for (int t = 0; t < TT; ++t) {
        float xwn = sxw[4 * (t + 1)];        // prefetch (pad slot at t=63)

        // ---- y_w = xw + sum_j w_in[w,j] h_j : row-DPP (4 j) + permlane^16
        float p = hh * wh;
        float s = p + ROW_ROR(p, 4);
        s = s + ROW_ROR(s, 8);
        const float y = xwv + s + permx16(s, lane);

        // ---- per-wire basis via quad broadcast
        const float u = __cosf(y), v = __sinf(y);
        const float u0 = QUAD_BCAST(u, 0x00), u1 = QUAD_BCAST(u, 0x55);
        const float u2 = QUAD_BCAST(u, 0xAA), u3 = QUAD_BCAST(u, 0xFF);
        const float v0 = QUAD_BCAST(v, 0x00), v1 = QUAD_BCAST(v, 0x55);
        const float v2 = QUAD_BCAST(v, 0xAA), v3 = QUAD_BCAST(v, 0xFF);

        // ---- 81-term factored contraction; level-3 packed (v_pk_fma_f32)
        const v2f u3p = {u3, u3}, v3p = {v3, v3};
        v2f cp[14];
        #pragma unroll
        for (int i = 0; i < 13; ++i)
            cp[i] = FMA2(u3p, E1[i], FMA2(v3p, E2[i], E0[i]));
        const float c3t = fmaf(u3, e1s, fmaf(v3, e2s, e0s));
        float c2v[9];
        #pragma unroll
        for (int i = 0; i < 9; ++i)
            c2v[i] = fmaf(u2, C3V(3*i + 1), fmaf(v2, C3V(3*i + 2), C3V(3*i)));
        const float c1a = fmaf(u1, c2v[1], fmaf(v1, c2v[2], c2v[0]));
        const float c1b = fmaf(u1, c2v[4], fmaf(v1, c2v[5], c2v[3]));
        const float c1c = fmaf(u1, c2v[7], fmaf(v1, c2v[8], c2v[6]));
        const float a = fmaf(u0, c1b, fmaf(v0, c1c, c1a));

        // ---- activation (sigmoid; tanh = 2*sig(2a)-1 for gate u)
        const float sg  = __builtin_amdgcn_rcpf(1.0f + __expf(-inS * a));
        const float act = fmaf(sg, outS, outB);

        // ---- gather the quad's 4 gate values (DPP)
        const float fv = QUAD_BCAST(act, 0x00), iv = QUAD_BCAST(act, 0x55);
        const float gv = QUAD_BCAST(act, 0xAA), ov = QUAD_BCAST(act, 0xFF);

        // ---- cell update for unit j
        cc = fmaf(fv, cc, iv * gv);
        const float th = fmaf(2.0f, __builtin_amdgcn_rcpf(1.0f + __expf(-2.0f * cc)), -1.0f);
        hh = ov * th;

        xwv = xwn;
    }

    // ---- out[elem] = h.w_fc + b_fc  (row-DPP + ^16 reduce over j)
    float pf = hh * wfc;
    float sf = pf + ROW_ROR(pf, 4);
    sf = sf + ROW_ROR(sf, 8);
    sf = sf + permx16(sf, lane);
    if ((lane & 31) == 0) out[blockIdx.x * 2 + e] = sf + b_fc[0];
}

extern "C" void kernel_launch(void* const* d_in, const int* in_sizes, int n_in,
                              void* d_out, int out_size, void* d_ws, size_t ws_size,
                              hipStream_t stream) {
    const float* x     = (const float*)d_in[0];
    const float* w_in  = (const float*)d_in[1];
    const float* b_in  = (const float*)d_in[2];
    const float* w_out = (const float*)d_in[3];
    const float* b_out = (const float*)d_in[4];
    const float* wq_f  = (const float*)d_in[5];
    const float* wq_i  = (const float*)d_in[6];
    const float* wq_u  = (const float*)d_in[7];
    const float* wq_o  = (const float*)d_in[8];
    const float* w_fc  = (const float*)d_in[9];
    const float* b_fc  = (const float*)d_in[10];
    float* out = (float*)d_out;
    (void)in_sizes; (void)n_in; (void)out_size; (void)d_ws; (void)ws_size;

    qlstm32p_kernel<<<BB / 2, 64, 0, stream>>>(x, w_in, b_in, w_out, b_out,
                                               wq_f, wq_i, wq_u, wq_o,
                                               w_fc, b_fc, out);
}